// Round 8
// baseline (8385.589 us; speedup 1.0000x reference)
//
#include <hip/hip_runtime.h>
#include <hip/hip_bf16.h>

#define T_TOTAL 1024
#define BATCH   64
#define HID     512

__device__ __forceinline__ float fast_sigmoid(float x) {
    return 1.f / (1.f + __expf(-x));
}
__device__ __forceinline__ float fast_tanh(float x) {
    float ax = fabsf(x);
    float e  = __expf(-2.f * ax);
    float t  = (1.f - e) / (1.f + e);
    return copysignf(t, x);
}

// ---------------------------------------------------------------------------
// GEMM: C[m,n] = sum_k A[rowg(m),k] * W[n,k] + bias[n]
// A row-major [*, K], W row-major [N, K] (i.e. computes A @ W^T + bias).
// ---------------------------------------------------------------------------
template<int BM, int BN, int TM, int TN>
__global__ __launch_bounds__(256, 2)
void gemm_bt_k(const float* __restrict__ A, const float* __restrict__ W,
               const float* __restrict__ bias, float* __restrict__ C,
               int K, int T, int Tc, int t0, int N)
{
    constexpr int BK = 16;
    constexpr int WSTR = BN + (BN / 32) * 4;
    static_assert(BM / TM == 16 && BN / TN == 16, "256 threads required");
    __shared__ float As[BK][BM + 4];
    __shared__ float Ws[BK][WSTR];

    const int tid = threadIdx.x;
    const int tx  = tid & 15;
    const int ty  = tid >> 4;
    const int m0  = blockIdx.y * BM;
    const int n0  = blockIdx.x * BN;
    const int nA  = tx * TN;
    const int nsw = nA + ((nA >> 5) << 2);

    float acc[TM][TN];
#pragma unroll
    for (int i = 0; i < TM; ++i)
#pragma unroll
        for (int j = 0; j < TN; ++j) acc[i][j] = 0.f;

    for (int k0 = 0; k0 < K; k0 += BK) {
#pragma unroll
        for (int i = 0; i < (BM * BK) / 1024; ++i) {
            int id = tid + (i << 8);
            int m  = id >> 2;
            int kq = (id & 3) << 2;
            int mloc = m0 + m;
            int rowg = (mloc / Tc) * T + t0 + (mloc % Tc);
            const float4 v = *reinterpret_cast<const float4*>(A + (size_t)rowg * K + k0 + kq);
            As[kq + 0][m] = v.x; As[kq + 1][m] = v.y;
            As[kq + 2][m] = v.z; As[kq + 3][m] = v.w;
        }
#pragma unroll
        for (int i = 0; i < (BN * BK) / 1024; ++i) {
            int id = tid + (i << 8);
            int n  = id >> 2;
            int kq = (id & 3) << 2;
            const float4 v = *reinterpret_cast<const float4*>(W + (size_t)(n0 + n) * K + k0 + kq);
            int np = n + ((n >> 5) << 2);
            Ws[kq + 0][np] = v.x; Ws[kq + 1][np] = v.y;
            Ws[kq + 2][np] = v.z; Ws[kq + 3][np] = v.w;
        }
        __syncthreads();
#pragma unroll
        for (int k = 0; k < BK; ++k) {
            float a[TM], b[TN];
#pragma unroll
            for (int i = 0; i < TM; i += 4)
                *reinterpret_cast<float4*>(&a[i]) =
                    *reinterpret_cast<const float4*>(&As[k][ty * TM + i]);
#pragma unroll
            for (int j = 0; j < TN; j += 4)
                *reinterpret_cast<float4*>(&b[j]) =
                    *reinterpret_cast<const float4*>(&Ws[k][nsw + j]);
#pragma unroll
            for (int i = 0; i < TM; ++i)
#pragma unroll
                for (int j = 0; j < TN; ++j)
                    acc[i][j] = fmaf(a[i], b[j], acc[i][j]);
        }
        __syncthreads();
    }
#pragma unroll
    for (int i = 0; i < TM; ++i) {
        const size_t crow = (size_t)(m0 + ty * TM + i) * N + n0 + nA;
#pragma unroll
        for (int j = 0; j < TN; j += 4) {
            float4 bv = *reinterpret_cast<const float4*>(bias + n0 + nA + j);
            float4 v;
            v.x = acc[i][j + 0] + bv.x; v.y = acc[i][j + 1] + bv.y;
            v.z = acc[i][j + 2] + bv.z; v.w = acc[i][j + 3] + bv.w;
            *reinterpret_cast<float4*>(C + crow + j) = v;
        }
    }
}

// ---------------------------------------------------------------------------
// Persistent GRU scan (one T-chunk of one layer) — R18.
// = R17 (256 blocks x 512 threads, 32 dims/block, 4 batches/group, 96
// weight floats/lane) + OPACIFIED WEIGHTS. R17's counters showed
// VGPR_Count=84 with a 96-float weight array under a 256-VGPR budget:
// the allocator was REMATERIALIZING the invariant weight loads inside the
// step loop (re-reading ~384B/lane/step from L2 — the hidden cost that
// kept every version since R11 off the FMA floor). The empty inline-asm
// "+v" pass-through below makes the loaded values opaque: remat becomes
// illegal, and with ~160 regs live vs a 256 budget the only sane choice
// is to keep them in VGPRs. Everything else is identical to R17 (passed,
// absmax 4.9e-4): protocol, hbuf [16grp][2slot][4b][512], tags, slot
// parity, per-wave poll = MAC footprint, merged reduce+gates.
// ---------------------------------------------------------------------------
__global__ __launch_bounds__(512, 2)
void gru_scan(const float* __restrict__ xg,    // chunk-local [64][Tc][1536]
              const float* __restrict__ w_hh,  // [1536][512]
              const float* __restrict__ b_hh,  // [1536]
              float* __restrict__ y,           // [64][1024][512]
              unsigned long long* __restrict__ hbuf, // [16 grp][2 slot][4 b][512]
              int t0, int Tc, int tagbase)
{
    const int tid = threadIdx.x;
    const int grp = blockIdx.x & 15;      // 16 blocks of a group
    const int os  = blockIdx.x >> 4;      // output slice 0..15
    const int D0  = os << 5;              // 32 h-dims per block
    const int d   = tid & 63;             // lane
    const int w   = tid >> 6;             // wave 0..7
    const int loc = d & 31;               // out-dim within block
    const int kh  = d >> 5;               // K-half within wave's 64-chunk
    const int k0  = w * 64 + kh * 32;     // this lane's K-range start
    const int bg  = grp << 2;             // 4 batch rows per group

    __shared__ float h_lds[2][4 * 512];   // [slot][b*512 + dim]
    __shared__ float part[2][16 * 384];   // [slot][p(16)][g(3)][b(4)*32+loc]

    // persistent weights: w4[g][j] = w_hh[g*512 + D0+loc][k0 + 4j ..]
    float4 w4[3][8];
#pragma unroll
    for (int g = 0; g < 3; ++g) {
        const float* wr = w_hh + (size_t)(g * 512 + D0 + loc) * 512 + k0;
#pragma unroll
        for (int j = 0; j < 8; ++j)
            w4[g][j] = *reinterpret_cast<const float4*>(wr + (j << 2));
    }
    // OPACIFY: break the remat chain. After this, the compiler cannot
    // re-derive these values from memory; it must keep them live.
#pragma unroll
    for (int g = 0; g < 3; ++g)
#pragma unroll
        for (int j = 0; j < 8; ++j)
            asm volatile("" : "+v"(w4[g][j].x), "+v"(w4[g][j].y),
                              "+v"(w4[g][j].z), "+v"(w4[g][j].w));

    // gate-thread biases (tid<128: b = tid>>5, dim = D0 + (tid&31))
    float bias_r = 0.f, bias_z = 0.f, bias_n = 0.f;
    if (tid < 128) {
        bias_r = b_hh[       D0 + loc];
        bias_z = b_hh[ 512 + D0 + loc];
        bias_n = b_hh[1024 + D0 + loc];
    }

    for (int tl = 0; tl < Tc; ++tl) {
        const int tg = t0 + tl;
        float* hl = h_lds[tl & 1];
        float* pt = part[tl & 1];

        // gate threads prefetch this step's xg early (hidden behind poll+MAC)
        float xr = 0.f, xz = 0.f, xn = 0.f;
        if (tid < 128) {
            const int b = tid >> 5;
            const size_t rowo = ((size_t)(bg + b) * Tc + tl) * 1536 + D0 + loc;
            xr = xg[rowo];
            xz = xg[rowo + 512];
            xn = xg[rowo + 1024];
        }

        // per-lane poll: 4 words = (batch q, dim tid) for q=0..3.
        // Wave w covers dims [64w,64w+64) x 4 batches = exactly its MAC
        // footprint (wave-local RAW; lgkmcnt drain below, no barrier).
        if (tg == 0) {
#pragma unroll
            for (int q = 0; q < 4; ++q)
                hl[q * 512 + tid] = 0.f;
        } else {
            const unsigned long long* hsrc =
                hbuf + (size_t)grp * 4096 + ((tg - 1) & 1) * 2048 + tid;
            const unsigned int tagexp = (unsigned int)(tagbase + tl - 1);
            unsigned long long v0, v1, v2, v3;
            for (;;) {
                v0 = __hip_atomic_load(hsrc,
                        __ATOMIC_RELAXED, __HIP_MEMORY_SCOPE_AGENT);
                v1 = __hip_atomic_load(hsrc + 512,
                        __ATOMIC_RELAXED, __HIP_MEMORY_SCOPE_AGENT);
                v2 = __hip_atomic_load(hsrc + 1024,
                        __ATOMIC_RELAXED, __HIP_MEMORY_SCOPE_AGENT);
                v3 = __hip_atomic_load(hsrc + 1536,
                        __ATOMIC_RELAXED, __HIP_MEMORY_SCOPE_AGENT);
                const int ok = (int)(((unsigned int)(v0 >> 32) == tagexp) &
                                     ((unsigned int)(v1 >> 32) == tagexp) &
                                     ((unsigned int)(v2 >> 32) == tagexp) &
                                     ((unsigned int)(v3 >> 32) == tagexp));
                if (__all(ok)) break;
            }
            union { unsigned int u; float f; } c0, c1, c2, c3;
            c0.u = (unsigned int)v0;
            c1.u = (unsigned int)v1;
            c2.u = (unsigned int)v2;
            c3.u = (unsigned int)v3;
            hl[       tid] = c0.f;
            hl[ 512 + tid] = c1.f;
            hl[1024 + tid] = c2.f;
            hl[1536 + tid] = c3.f;
        }
        // wave-local LDS RAW: drain lgkmcnt before the broadcast reads
        __builtin_amdgcn_s_waitcnt(0xC07F);   // lgkmcnt(0) only

        // register MAC over this lane's 32-wide K range, 4 batches
        float acc[3][4];
#pragma unroll
        for (int g = 0; g < 3; ++g)
#pragma unroll
            for (int b = 0; b < 4; ++b) acc[g][b] = 0.f;
        const float* hb = hl + k0;
#pragma unroll
        for (int j = 0; j < 8; ++j) {
            const float4 h0 = *reinterpret_cast<const float4*>(hb +        (j << 2));
            const float4 h1 = *reinterpret_cast<const float4*>(hb +  512 + (j << 2));
            const float4 h2 = *reinterpret_cast<const float4*>(hb + 1024 + (j << 2));
            const float4 h3 = *reinterpret_cast<const float4*>(hb + 1536 + (j << 2));
#pragma unroll
            for (int g = 0; g < 3; ++g) {
                const float4 wv = w4[g][j];
                acc[g][0] = fmaf(wv.x, h0.x, acc[g][0]);
                acc[g][0] = fmaf(wv.y, h0.y, acc[g][0]);
                acc[g][0] = fmaf(wv.z, h0.z, acc[g][0]);
                acc[g][0] = fmaf(wv.w, h0.w, acc[g][0]);
                acc[g][1] = fmaf(wv.x, h1.x, acc[g][1]);
                acc[g][1] = fmaf(wv.y, h1.y, acc[g][1]);
                acc[g][1] = fmaf(wv.z, h1.z, acc[g][1]);
                acc[g][1] = fmaf(wv.w, h1.w, acc[g][1]);
                acc[g][2] = fmaf(wv.x, h2.x, acc[g][2]);
                acc[g][2] = fmaf(wv.y, h2.y, acc[g][2]);
                acc[g][2] = fmaf(wv.z, h2.z, acc[g][2]);
                acc[g][2] = fmaf(wv.w, h2.w, acc[g][2]);
                acc[g][3] = fmaf(wv.x, h3.x, acc[g][3]);
                acc[g][3] = fmaf(wv.y, h3.y, acc[g][3]);
                acc[g][3] = fmaf(wv.z, h3.z, acc[g][3]);
                acc[g][3] = fmaf(wv.w, h3.w, acc[g][3]);
            }
        }
        {
            // part[p][g][b*32+loc], p = w*2+kh (p ascending == K ascending)
            float* pp = pt + (w * 2 + kh) * 384 + loc;
#pragma unroll
            for (int g = 0; g < 3; ++g)
#pragma unroll
                for (int b = 0; b < 4; ++b)
                    pp[g * 128 + b * 32] = acc[g][b];
        }
        __syncthreads();   // the ONLY barrier per step

        // merged reduce + gates + tagged publish (fire-and-forget).
        // FP order: bias first, then p ascending (= K ascending).
        if (tid < 128) {
            const int b = tid >> 5;
            float sr = bias_r, sz = bias_z, sn = bias_n;
#pragma unroll
            for (int p = 0; p < 16; ++p) {
                sr += pt[p * 384 +       tid];   // g*128 + b*32+loc == tid for g=0
                sz += pt[p * 384 + 128 + tid];
                sn += pt[p * 384 + 256 + tid];
            }
            const int D = D0 + loc;
            const float hp = hl[b * 512 + D];
            const float r  = fast_sigmoid(xr + sr);
            const float z  = fast_sigmoid(xz + sz);
            const float nv = fast_tanh(xn + r * sn);
            const float h  = (1.f - z) * nv + z * hp;
            union { float f; unsigned int u; } cv; cv.f = h;
            const unsigned long long pk =
                ((unsigned long long)(unsigned int)(tagbase + tl) << 32) | cv.u;
            unsigned long long* hdst =
                hbuf + (size_t)grp * 4096 + (tg & 1) * 2048 + b * 512 + D;
            __hip_atomic_store(hdst, pk, __ATOMIC_RELAXED,
                               __HIP_MEMORY_SCOPE_AGENT);
            y[((size_t)(bg + b) * T_TOTAL + tg) * HID + D] = h;
        }
        // no trailing barrier: h_lds/part are double-buffered by step parity.
    }
}

// ---------------------------------------------------------------------------
extern "C" void kernel_launch(void* const* d_in, const int* in_sizes, int n_in,
                              void* d_out, int out_size, void* d_ws, size_t ws_size,
                              hipStream_t stream)
{
    const float* x       = (const float*)d_in[0];
    const float* w_ih[2] = {(const float*)d_in[1], (const float*)d_in[5]};
    const float* w_hh[2] = {(const float*)d_in[2], (const float*)d_in[6]};
    const float* b_ih[2] = {(const float*)d_in[3], (const float*)d_in[7]};
    const float* b_hh[2] = {(const float*)d_in[4], (const float*)d_in[8]};
    const float* fc_w    = (const float*)d_in[9];
    const float* fc_b    = (const float*)d_in[10];
    float* out = (float*)d_out;

    const size_t Y_BYTES = (size_t)BATCH * T_TOTAL * HID * 4;   // 128 MiB
    const size_t H_BYTES = (size_t)16 * 2 * 4 * 512 * 8;        // 512 KiB (u64)
    int Tc = 256;
    while (Tc > 32) {
        size_t need = (size_t)BATCH * Tc * 1536 * 4 + Y_BYTES + H_BYTES;
        if (need <= ws_size) break;
        Tc >>= 1;
    }

    char* p = (char*)d_ws;
    float* xg_buf = (float*)p;                 p += (size_t)BATCH * Tc * 1536 * 4;
    float* y_buf  = (float*)p;                 p += Y_BYTES;
    unsigned long long* hbuf = (unsigned long long*)p;

    const int nchunks = T_TOTAL / Tc;
    for (int L = 0; L < 2; ++L) {
        const float* A = L ? y_buf : x;
        const int K    = L ? HID : 64;
        for (int c = 0; c < nchunks; ++c) {
            dim3 g1(1536 / 128, (BATCH * Tc) / 128);
            gemm_bt_k<128, 128, 8, 8><<<g1, 256, 0, stream>>>(
                A, w_ih[L], b_ih[L], xg_buf, K, T_TOTAL, Tc, c * Tc, 1536);
            gru_scan<<<256, 512, 0, stream>>>(
                xg_buf, w_hh[L], b_hh[L], y_buf, hbuf,
                c * Tc, Tc, (L << 11) + c * Tc);
        }
    }
    dim3 g2(64 / 64, (BATCH * T_TOTAL) / 128);
    gemm_bt_k<128, 64, 8, 4><<<g2, 256, 0, stream>>>(
        y_buf, fc_w, fc_b, out, HID, BATCH * T_TOTAL, BATCH * T_TOTAL, 0, 64);
}

// Round 9
// 6520.123 us; speedup vs baseline: 1.2861x; 1.2861x over previous
//
#include <hip/hip_runtime.h>
#include <hip/hip_bf16.h>

#define T_TOTAL 1024
#define BATCH   64
#define HID     512

__device__ __forceinline__ float fast_sigmoid(float x) {
    return 1.f / (1.f + __expf(-x));
}
__device__ __forceinline__ float fast_tanh(float x) {
    float ax = fabsf(x);
    float e  = __expf(-2.f * ax);
    float t  = (1.f - e) / (1.f + e);
    return copysignf(t, x);
}

// ---------------------------------------------------------------------------
// GEMM: C[m,n] = sum_k A[rowg(m),k] * W[n,k] + bias[n]
// A row-major [*, K], W row-major [N, K] (i.e. computes A @ W^T + bias).
// ---------------------------------------------------------------------------
template<int BM, int BN, int TM, int TN>
__global__ __launch_bounds__(256, 2)
void gemm_bt_k(const float* __restrict__ A, const float* __restrict__ W,
               const float* __restrict__ bias, float* __restrict__ C,
               int K, int T, int Tc, int t0, int N)
{
    constexpr int BK = 16;
    constexpr int WSTR = BN + (BN / 32) * 4;
    static_assert(BM / TM == 16 && BN / TN == 16, "256 threads required");
    __shared__ float As[BK][BM + 4];
    __shared__ float Ws[BK][WSTR];

    const int tid = threadIdx.x;
    const int tx  = tid & 15;
    const int ty  = tid >> 4;
    const int m0  = blockIdx.y * BM;
    const int n0  = blockIdx.x * BN;
    const int nA  = tx * TN;
    const int nsw = nA + ((nA >> 5) << 2);

    float acc[TM][TN];
#pragma unroll
    for (int i = 0; i < TM; ++i)
#pragma unroll
        for (int j = 0; j < TN; ++j) acc[i][j] = 0.f;

    for (int k0 = 0; k0 < K; k0 += BK) {
#pragma unroll
        for (int i = 0; i < (BM * BK) / 1024; ++i) {
            int id = tid + (i << 8);
            int m  = id >> 2;
            int kq = (id & 3) << 2;
            int mloc = m0 + m;
            int rowg = (mloc / Tc) * T + t0 + (mloc % Tc);
            const float4 v = *reinterpret_cast<const float4*>(A + (size_t)rowg * K + k0 + kq);
            As[kq + 0][m] = v.x; As[kq + 1][m] = v.y;
            As[kq + 2][m] = v.z; As[kq + 3][m] = v.w;
        }
#pragma unroll
        for (int i = 0; i < (BN * BK) / 1024; ++i) {
            int id = tid + (i << 8);
            int n  = id >> 2;
            int kq = (id & 3) << 2;
            const float4 v = *reinterpret_cast<const float4*>(W + (size_t)(n0 + n) * K + k0 + kq);
            int np = n + ((n >> 5) << 2);
            Ws[kq + 0][np] = v.x; Ws[kq + 1][np] = v.y;
            Ws[kq + 2][np] = v.z; Ws[kq + 3][np] = v.w;
        }
        __syncthreads();
#pragma unroll
        for (int k = 0; k < BK; ++k) {
            float a[TM], b[TN];
#pragma unroll
            for (int i = 0; i < TM; i += 4)
                *reinterpret_cast<float4*>(&a[i]) =
                    *reinterpret_cast<const float4*>(&As[k][ty * TM + i]);
#pragma unroll
            for (int j = 0; j < TN; j += 4)
                *reinterpret_cast<float4*>(&b[j]) =
                    *reinterpret_cast<const float4*>(&Ws[k][nsw + j]);
#pragma unroll
            for (int i = 0; i < TM; ++i)
#pragma unroll
                for (int j = 0; j < TN; ++j)
                    acc[i][j] = fmaf(a[i], b[j], acc[i][j]);
        }
        __syncthreads();
    }
#pragma unroll
    for (int i = 0; i < TM; ++i) {
        const size_t crow = (size_t)(m0 + ty * TM + i) * N + n0 + nA;
#pragma unroll
        for (int j = 0; j < TN; j += 4) {
            float4 bv = *reinterpret_cast<const float4*>(bias + n0 + nA + j);
            float4 v;
            v.x = acc[i][j + 0] + bv.x; v.y = acc[i][j + 1] + bv.y;
            v.z = acc[i][j + 2] + bv.z; v.w = acc[i][j + 3] + bv.w;
            *reinterpret_cast<float4*>(C + crow + j) = v;
        }
    }
}

// ---------------------------------------------------------------------------
// R11 scan body, verbatim (proven: 637us/chunk, 128 VGPR, passed).
// 256 blocks per scan instance; 8 waves; per-wave dataflow pipelining,
// branch-free poll, ONE barrier/step, parity double-buffered part[]/h_lds,
// merged reduce+gates, fire-and-forget tagged publish.
// ---------------------------------------------------------------------------
__device__ __forceinline__
void scan_body(int bid,
               const float* __restrict__ xg,    // chunk-local [64][Tc][1536]
               const float* __restrict__ w_hh,  // [1536][512]
               const float* __restrict__ b_hh,  // [1536]
               float* __restrict__ y,           // [64][1024][512]
               unsigned long long* __restrict__ hbuf, // [32 grp][2 slot][2 b][512]
               int t0, int Tc, int tagbase)
{
    const int tid = threadIdx.x;
    const int grp = bid & 31;             // 8 blocks of a group
    const int os  = bid >> 5;             // output slice 0..7
    const int D0  = os << 6;              // 64 h-dims per block
    const int d   = tid & 63;             // lane
    const int kc  = tid >> 6;             // wave index == its K-chunk
    const int bg  = grp << 1;             // 2 batch rows per group

    __shared__ float h_lds[2][1024];      // [slot][b*512 + D]
    __shared__ float part[2][8 * 392];    // [slot][kc][g*128 + b*64 + d]

    // persistent weights: w4[g][j] = w_hh[g*512+D0+d][kc*64 + 4j ..]
    float4 w4[3][16];
#pragma unroll
    for (int g = 0; g < 3; ++g) {
        const float* wr = w_hh + (size_t)(g * 512 + D0 + d) * 512 + kc * 64;
#pragma unroll
        for (int j = 0; j < 16; ++j)
            w4[g][j] = *reinterpret_cast<const float4*>(wr + (j << 2));
    }
    // gate-thread biases (merged reduce+gates)
    float bias_r = 0.f, bias_z = 0.f, bias_n = 0.f;
    if (tid < 128) {
        bias_r = b_hh[       D0 + d];
        bias_z = b_hh[ 512 + D0 + d];
        bias_n = b_hh[1024 + D0 + d];
    }
    const int b_loc = tid >> 6;           // gate threads (tid<128): row 0..1

    for (int tl = 0; tl < Tc; ++tl) {
        const int tg = t0 + tl;
        float* hl = h_lds[tl & 1];
        float* pt = part[tl & 1];

        // gate threads prefetch this step's xg early (hidden behind poll)
        float xr = 0.f, xz = 0.f, xn = 0.f;
        if (tid < 128) {
            const size_t rowo = ((size_t)(bg + b_loc) * Tc + tl) * 1536 + D0 + d;
            xr = xg[rowo];
            xz = xg[rowo + 512];
            xn = xg[rowo + 1024];
        }

        // per-wave staging: wave kc polls ONLY publisher kc's 128 words.
        if (tg == 0) {
            hl[      kc * 64 + d] = 0.f;
            hl[512 + kc * 64 + d] = 0.f;
        } else {
            const unsigned long long* hsrc =
                hbuf + (size_t)(grp * 2 + ((tg - 1) & 1)) * 1024 + kc * 64;
            const unsigned int tagexp = (unsigned int)(tagbase + tl - 1);
            unsigned long long v0, v1;
            for (;;) {
                v0 = __hip_atomic_load(hsrc + d,
                        __ATOMIC_RELAXED, __HIP_MEMORY_SCOPE_AGENT);
                v1 = __hip_atomic_load(hsrc + 512 + d,
                        __ATOMIC_RELAXED, __HIP_MEMORY_SCOPE_AGENT);
                const int ok = (int)(((unsigned int)(v0 >> 32) == tagexp) &
                                     ((unsigned int)(v1 >> 32) == tagexp));
                if (__all(ok)) break;
            }
            union { unsigned int u; float f; } c0, c1;
            c0.u = (unsigned int)v0;
            c1.u = (unsigned int)v1;
            hl[      kc * 64 + d] = c0.f;
            hl[512 + kc * 64 + d] = c1.f;
        }
        // wave-local LDS RAW: drain lgkmcnt before the broadcast reads
        __builtin_amdgcn_s_waitcnt(0xC07F);   // lgkmcnt(0) only

        // register MAC over this wave's 64-wide K chunk (broadcast reads)
        float acc[3][2];
#pragma unroll
        for (int g = 0; g < 3; ++g) { acc[g][0] = 0.f; acc[g][1] = 0.f; }
        const float* hb = hl + kc * 64;
#pragma unroll
        for (int j = 0; j < 16; ++j) {
            const float4 h0 = *reinterpret_cast<const float4*>(hb + (j << 2));
            const float4 h1 = *reinterpret_cast<const float4*>(hb + 512 + (j << 2));
#pragma unroll
            for (int g = 0; g < 3; ++g) {
                const float4 wv = w4[g][j];
                acc[g][0] = fmaf(wv.x, h0.x, acc[g][0]);
                acc[g][0] = fmaf(wv.y, h0.y, acc[g][0]);
                acc[g][0] = fmaf(wv.z, h0.z, acc[g][0]);
                acc[g][0] = fmaf(wv.w, h0.w, acc[g][0]);
                acc[g][1] = fmaf(wv.x, h1.x, acc[g][1]);
                acc[g][1] = fmaf(wv.y, h1.y, acc[g][1]);
                acc[g][1] = fmaf(wv.z, h1.z, acc[g][1]);
                acc[g][1] = fmaf(wv.w, h1.w, acc[g][1]);
            }
        }
        {
            float* pp = pt + kc * 392 + d;
#pragma unroll
            for (int g = 0; g < 3; ++g) {
                pp[g * 128]      = acc[g][0];
                pp[g * 128 + 64] = acc[g][1];
            }
        }
        __syncthreads();   // the ONLY barrier per step

        // merged reduce + gates + tagged publish (fire-and-forget).
        // FP order identical to R8-R11: bias first, then q ascending.
        if (tid < 128) {
            float sr = bias_r, sz = bias_z, sn = bias_n;
#pragma unroll
            for (int q = 0; q < 8; ++q) {
                sr += pt[q * 392 +       tid];
                sz += pt[q * 392 + 128 + tid];
                sn += pt[q * 392 + 256 + tid];
            }
            const int D = D0 + d;
            const float hp = hl[b_loc * 512 + D];
            const float r  = fast_sigmoid(xr + sr);
            const float z  = fast_sigmoid(xz + sz);
            const float nv = fast_tanh(xn + r * sn);
            const float h  = (1.f - z) * nv + z * hp;
            union { float f; unsigned int u; } cv; cv.f = h;
            const unsigned long long pk =
                ((unsigned long long)(unsigned int)(tagbase + tl) << 32) | cv.u;
            unsigned long long* hdst =
                hbuf + (size_t)(grp * 2 + (tg & 1)) * 1024 + b_loc * 512 + D;
            __hip_atomic_store(hdst, pk, __ATOMIC_RELAXED,
                               __HIP_MEMORY_SCOPE_AGENT);
            y[((size_t)(bg + b_loc) * T_TOTAL + tg) * HID + D] = h;
        }
        // no trailing barrier: h_lds/part are double-buffered by step parity.
    }
}

// ---------------------------------------------------------------------------
// R19: dual-scan fused launch — LAYER PIPELINING. scan(L0,c+1) and
// scan(L1,c) are data-independent (gemm(L1,c), which consumes scan(L0,c)'s
// y, completes before this launch on the same stream). Blocks 0..255 run
// half A, 256..511 half B — SAME body, uniform 128 VGPR (launch_bounds'
// 2nd arg = min blocks/CU on this toolchain: (512,2) caps at 128, R11's
// body compiles to exactly that). 2 blocks/CU guaranteed (LDS 65KB/CU,
// 16 waves/CU) -> all 512 co-resident; each half self-contained (its 32
// groups live within its own 256 blocks; (256+g)%8 == g%8 keeps the
// same-XCD group mapping for half B). Separate hbuf per layer; shared
// y_buf is safe (L1 overwrites chunk c only after gemm(L1,c) read it;
// L0 writes chunk c+1 — disjoint). Worst case (allocator >128 VGPR +
// in-order dispatch): halves serialize, perf == R11, no deadlock.
// ---------------------------------------------------------------------------
__global__ __launch_bounds__(512, 2)
void gru_scan2(const float* __restrict__ xgA, const float* __restrict__ xgB,
               const float* __restrict__ whhA, const float* __restrict__ whhB,
               const float* __restrict__ bhhA, const float* __restrict__ bhhB,
               float* __restrict__ y,
               unsigned long long* __restrict__ hbufA,
               unsigned long long* __restrict__ hbufB,
               int t0A, int t0B, int tagA, int tagB, int Tc)
{
    const int half = blockIdx.x >> 8;
    const int bid  = blockIdx.x & 255;
    const float* xg  = half ? xgB  : xgA;
    const float* whh = half ? whhB : whhA;
    const float* bhh = half ? bhhB : bhhA;
    unsigned long long* hb = half ? hbufB : hbufA;
    const int t0 = half ? t0B  : t0A;
    const int tb = half ? tagB : tagA;
    scan_body(bid, xg, whh, bhh, y, hb, t0, Tc, tb);
}

// ---------------------------------------------------------------------------
extern "C" void kernel_launch(void* const* d_in, const int* in_sizes, int n_in,
                              void* d_out, int out_size, void* d_ws, size_t ws_size,
                              hipStream_t stream)
{
    const float* x       = (const float*)d_in[0];
    const float* w_ih[2] = {(const float*)d_in[1], (const float*)d_in[5]};
    const float* w_hh[2] = {(const float*)d_in[2], (const float*)d_in[6]};
    const float* b_ih[2] = {(const float*)d_in[3], (const float*)d_in[7]};
    const float* b_hh[2] = {(const float*)d_in[4], (const float*)d_in[8]};
    const float* fc_w    = (const float*)d_in[9];
    const float* fc_b    = (const float*)d_in[10];
    float* out = (float*)d_out;

    const size_t Y_BYTES = (size_t)BATCH * T_TOTAL * HID * 4;   // 128 MiB
    const size_t H_BYTES = (size_t)32 * 2 * 2 * 512 * 8;        // 512 KiB (u64)
    // two xg buffers (one per layer-stream) + y + two hbuf regions
    int Tc = 256;
    while (Tc > 32) {
        size_t need = 2 * (size_t)BATCH * Tc * 1536 * 4 + Y_BYTES + 2 * H_BYTES;
        if (need <= ws_size) break;
        Tc >>= 1;
    }

    char* p = (char*)d_ws;
    float* xgA = (float*)p;                    p += (size_t)BATCH * Tc * 1536 * 4;
    float* xgB = (float*)p;                    p += (size_t)BATCH * Tc * 1536 * 4;
    float* y_buf = (float*)p;                  p += Y_BYTES;
    unsigned long long* hbufA = (unsigned long long*)p;  p += H_BYTES;
    unsigned long long* hbufB = (unsigned long long*)p;

    const int nchunks = T_TOTAL / Tc;
    dim3 gg(1536 / 128, (BATCH * Tc) / 128);

    // software pipeline over stages s = 0..nchunks:
    //   stage s runs scan(L0,s) [if s<nchunks]  ||  scan(L1,s-1) [if s>=1],
    //   each preceded (same stream) by its xg GEMM.
    for (int s = 0; s <= nchunks; ++s) {
        const bool hasA = (s < nchunks);
        const bool hasB = (s >= 1);
        if (hasA)
            gemm_bt_k<128, 128, 8, 8><<<gg, 256, 0, stream>>>(
                x, w_ih[0], b_ih[0], xgA, 64, T_TOTAL, Tc, s * Tc, 1536);
        if (hasB)
            gemm_bt_k<128, 128, 8, 8><<<gg, 256, 0, stream>>>(
                y_buf, w_ih[1], b_ih[1], xgB, HID, T_TOTAL, Tc, (s - 1) * Tc, 1536);

        if (hasA && hasB) {
            gru_scan2<<<512, 512, 0, stream>>>(
                xgA, xgB, w_hh[0], w_hh[1], b_hh[0], b_hh[1], y_buf,
                hbufA, hbufB,
                s * Tc, (s - 1) * Tc,
                s * Tc, (1 << 11) + (s - 1) * Tc, Tc);
        } else if (hasA) {
            gru_scan2<<<256, 512, 0, stream>>>(
                xgA, xgA, w_hh[0], w_hh[0], b_hh[0], b_hh[0], y_buf,
                hbufA, hbufA, s * Tc, s * Tc, s * Tc, s * Tc, Tc);
        } else {
            gru_scan2<<<256, 512, 0, stream>>>(
                xgB, xgB, w_hh[1], w_hh[1], b_hh[1], b_hh[1], y_buf,
                hbufB, hbufB, (s - 1) * Tc, (s - 1) * Tc,
                (1 << 11) + (s - 1) * Tc, (1 << 11) + (s - 1) * Tc, Tc);
        }
    }

    // FC epilogue
    dim3 g2(64 / 64, (BATCH * T_TOTAL) / 128);
    gemm_bt_k<128, 64, 8, 4><<<g2, 256, 0, stream>>>(
        y_buf, fc_w, fc_b, out, HID, BATCH * T_TOTAL, BATCH * T_TOTAL, 0, 64);
}